// Round 1
// baseline (369.267 us; speedup 1.0000x reference)
//
#include <hip/hip_runtime.h>

typedef unsigned short ushort_t;
typedef float f32x4 __attribute__((ext_vector_type(4)));
typedef short s16x8 __attribute__((ext_vector_type(8)));

#define BROWS 4096
#define DIMK  1024
#define RANKK 256
#define TROWS 16
#define GPAD  (RANKK + 8)   // padded g row (264 ushorts = 528 B, 16B-aligned rows)

#define DTF 0.01f
// THETA = 1/(2 - 2^(1/3))
#define THETAF 1.35120719195965763f
#define C1F    0.675603595979828816f   // THETA/2  (== C4)
#define C2F   (-0.175603595979828816f) // (1-THETA)/2  (== C3)
#define D1F    1.35120719195965763f    // THETA (== D3)
#define D2F   (-1.70241438391931526f)  // 1 - 2*THETA

__device__ __forceinline__ ushort_t f2bf(float f) {
    unsigned u = __builtin_bit_cast(unsigned, f);
    return (ushort_t)((u + 0x7FFFu + ((u >> 16) & 1u)) >> 16);
}

// ---------------------------------------------------------------------------
// Transpose + cast f32 -> bf16:  out[c][r] = bf16(in[r][c]),  in is [R][C].
// ---------------------------------------------------------------------------
__global__ void fr_transpose_cast(const float* __restrict__ in,
                                  ushort_t* __restrict__ out, int R, int C) {
    __shared__ float tile[32][33];
    int tiles_c = C >> 5;
    int tr = blockIdx.x / tiles_c;
    int tc = blockIdx.x % tiles_c;
    int tx = threadIdx.x & 31;
    int ty = threadIdx.x >> 5;  // 0..7
#pragma unroll
    for (int i = 0; i < 32; i += 8)
        tile[ty + i][tx] = in[(size_t)(tr * 32 + ty + i) * C + tc * 32 + tx];
    __syncthreads();
#pragma unroll
    for (int i = 0; i < 32; i += 8)
        out[(size_t)(tc * 32 + ty + i) * R + tr * 32 + tx] = f2bf(tile[tx][ty + i]);
}

// ---------------------------------------------------------------------------
// Fused Forest-Ruth integrator. One block = 16 rows, 512 threads (8 waves).
// Per accel j: x,v,force live in registers (MFMA C/D fragment ownership),
//   matmul1: h = v @ U   (v bf16 from swizzled LDS, Ut n-major from global)
//   matmul2: Gamma = (h*h) @ W (g bf16 via padded LDS, Wt n-major from global)
//   epilogue: v += d_j*dt*(force - Gamma);  x += c_{j+1}*dt*v;  vb <- bf16(v)
// ---------------------------------------------------------------------------
__global__ __launch_bounds__(512, 2) void fr_kernel(
    const float* __restrict__ x_in, const float* __restrict__ v_in,
    const float* __restrict__ f_in, const ushort_t* __restrict__ Ut,
    const ushort_t* __restrict__ Wt, const int* __restrict__ steps_p,
    float* __restrict__ out) {
    __shared__ ushort_t vb[TROWS * DIMK];   // bf16 v, XOR-swizzled rows
    __shared__ ushort_t gb[TROWS * GPAD];   // bf16 h^2, padded rows

    const int tid  = threadIdx.x;
    const int lane = tid & 63;
    const int wave = tid >> 6;          // 0..7
    const int m16  = lane & 15;         // frag col index (N for B/D, M for A)
    const int g4   = lane >> 4;         // 0..3 (k-group / m-group)
    const int row0 = blockIdx.x * TROWS;
    const int n_acc = 3 * steps_p[0];

    // fragment ownership: i = nt*4 + r;  m = g4*4 + r;  n = wave*128 + nt*16 + m16
    float vreg[32], xreg[32], freg[32];
#pragma unroll
    for (int nt = 0; nt < 8; ++nt) {
#pragma unroll
        for (int r = 0; r < 4; ++r) {
            const int m = g4 * 4 + r;
            const int n = wave * 128 + nt * 16 + m16;
            const size_t gi = (size_t)(row0 + m) * DIMK + n;
            const float v0 = v_in[gi];
            vreg[nt * 4 + r] = v0;
            xreg[nt * 4 + r] = x_in[gi] + (C1F * DTF) * v0;  // first x-substep folded
            freg[nt * 4 + r] = f_in[gi];
            vb[m * DIMK + (n ^ ((m & 7) << 3))] = f2bf(v0);
        }
    }
    __syncthreads();

    // precomputed B-pointers (16-byte frag loads)
    const s16x8* b0p = (const s16x8*)(Ut + (size_t)(wave * 32 + m16) * DIMK + g4 * 8);
    const s16x8* b1p = b0p + (16 * DIMK) / 8;
    const s16x8* bwp = (const s16x8*)(Wt + (size_t)(wave * 128 + m16) * RANKK + g4 * 8);
    const int n1a = wave * 32 + m16;
    const int n1b = n1a + 16;

    for (int j = 0; j < n_acc; ++j) {
        // ---- matmul1: h[16][256] = v @ U; this wave: ntiles {2w, 2w+1}
        f32x4 h0 = {0.f, 0.f, 0.f, 0.f}, h1 = {0.f, 0.f, 0.f, 0.f};
#pragma unroll 8
        for (int kk = 0; kk < DIMK / 32; ++kk) {
            const int k0 = kk * 32 + g4 * 8;
            const s16x8 a = *(const s16x8*)&vb[m16 * DIMK + (k0 ^ ((m16 & 7) << 3))];
            const s16x8 b0 = b0p[kk * 4];
            const s16x8 b1 = b1p[kk * 4];
            h0 = __builtin_amdgcn_mfma_f32_16x16x32_bf16(a, b0, h0, 0, 0, 0);
            h1 = __builtin_amdgcn_mfma_f32_16x16x32_bf16(a, b1, h1, 0, 0, 0);
        }
        // epilogue: g = h*h -> gb  (D frag: m = g4*4+r, n = n1a / n1b)
#pragma unroll
        for (int r = 0; r < 4; ++r) {
            const int m = g4 * 4 + r;
            gb[m * GPAD + n1a] = f2bf(h0[r] * h0[r]);
            gb[m * GPAD + n1b] = f2bf(h1[r] * h1[r]);
        }
        __syncthreads();  // B1: gb ready, vb reads done

        // ---- matmul2: Gamma[16][1024] = g @ W; this wave: 8 ntiles
        f32x4 acc[8];
#pragma unroll
        for (int nt = 0; nt < 8; ++nt) acc[nt] = (f32x4){0.f, 0.f, 0.f, 0.f};
#pragma unroll 2
        for (int kk = 0; kk < RANKK / 32; ++kk) {
            const int k0 = kk * 32 + g4 * 8;
            const s16x8 a = *(const s16x8*)&gb[m16 * GPAD + k0];
#pragma unroll
            for (int nt = 0; nt < 8; ++nt) {
                const s16x8 b = bwp[nt * 512 + kk * 4];
                acc[nt] = __builtin_amdgcn_mfma_f32_16x16x32_bf16(a, b, acc[nt], 0, 0, 0);
            }
        }

        // ---- epilogue: v update, x update, vb refresh
        const int ph = j - (j / 3) * 3;
        const float ddt = ((ph == 0) ? D1F : (ph == 1) ? D2F : D1F) * DTF;
        const float cdt = ((ph == 2) ? ((j == n_acc - 1) ? C1F : THETAF) : C2F) * DTF;
#pragma unroll
        for (int nt = 0; nt < 8; ++nt) {
#pragma unroll
            for (int r = 0; r < 4; ++r) {
                const int i = nt * 4 + r;
                const int m = g4 * 4 + r;
                const int n = wave * 128 + nt * 16 + m16;
                const float vn = vreg[i] + ddt * (freg[i] - acc[nt][r]);
                vreg[i] = vn;
                xreg[i] += cdt * vn;
                vb[m * DIMK + (n ^ ((m & 7) << 3))] = f2bf(vn);
            }
        }
        __syncthreads();  // B2: vb ready for next matmul1, gb reads done
    }

    // ---- write out: x then v, f32
    float* xo = out;
    float* vo = out + (size_t)BROWS * DIMK;
#pragma unroll
    for (int nt = 0; nt < 8; ++nt) {
#pragma unroll
        for (int r = 0; r < 4; ++r) {
            const int i = nt * 4 + r;
            const int m = g4 * 4 + r;
            const int n = wave * 128 + nt * 16 + m16;
            const size_t gi = (size_t)(row0 + m) * DIMK + n;
            xo[gi] = xreg[i];
            vo[gi] = vreg[i];
        }
    }
}

extern "C" void kernel_launch(void* const* d_in, const int* in_sizes, int n_in,
                              void* d_out, int out_size, void* d_ws, size_t ws_size,
                              hipStream_t stream) {
    const float* x = (const float*)d_in[0];
    const float* v = (const float*)d_in[1];
    const float* f = (const float*)d_in[2];
    const float* U = (const float*)d_in[3];   // [1024][256]
    const float* W = (const float*)d_in[4];   // [256][1024]
    const int* steps = (const int*)d_in[5];

    ushort_t* Ut = (ushort_t*)d_ws;                    // [256][1024] bf16, Ut[r][k]=U[k][r]
    ushort_t* Wt = Ut + (size_t)RANKK * DIMK;          // [1024][256] bf16, Wt[d][r]=W[r][d]
    float* out = (float*)d_out;

    fr_transpose_cast<<<(DIMK / 32) * (RANKK / 32), 256, 0, stream>>>(U, Ut, DIMK, RANKK);
    fr_transpose_cast<<<(RANKK / 32) * (DIMK / 32), 256, 0, stream>>>(W, Wt, RANKK, DIMK);
    fr_kernel<<<BROWS / TROWS, 512, 0, stream>>>(x, v, f, Ut, Wt, steps, out);
}